// Round 7
// baseline (1047.684 us; speedup 1.0000x reference)
//
#include <hip/hip_runtime.h>
#include <cstdint>
#include <cstddef>

typedef __bf16 bf16x8 __attribute__((ext_vector_type(8)));
typedef float f32x4 __attribute__((ext_vector_type(4)));
typedef unsigned short ushortx8 __attribute__((ext_vector_type(8)));

// float -> bf16, round-half-up
__device__ __forceinline__ unsigned short f2bf(float f) {
  union { float f; unsigned int u; } v; v.f = f;
  return (unsigned short)((v.u + 0x8000u) >> 16);
}

// GELU via 0.5*(1+tanh(t)) == sigmoid(2t); same function as rounds 1-5.
__device__ __forceinline__ float gelu_s(float x) {
  float x2 = x * x;
  float p = __builtin_fmaf(x2, -0.10294324f, -2.30220819f);
  float e = __builtin_amdgcn_exp2f(x * p);
  return x * __builtin_amdgcn_rcpf(1.0f + e);
}

// async global->LDS, 16B/lane. LDS dest is wave-uniform base + lane*16.
#define GLOAD16(gsrc, ldst)                                                  \
  __builtin_amdgcn_global_load_lds(                                          \
      (const __attribute__((address_space(1))) unsigned int*)(gsrc),         \
      (__attribute__((address_space(3))) unsigned int*)(uintptr_t)(          \
          (char*)(ldst)),                                                    \
      16, 0, 0)

// Swizzled tile: 16B chunk (row R, col8 C in [0,8)) at
// (R>>5)*4096 + ((R&31)*8 + (C ^ (R&7)))*16. Staging lane tid sources col8
// (tid&7)^((tid>>3)&7); 16-row fragment reads hit all 8 bank quads.
#define SWZ_FRAG(base, R, C8)                                                \
  (*(const bf16x8*)((base) + (((R) >> 5) * 4096) +                           \
                    ((((R)&31) * 8 + ((C8) ^ ((R)&7))) * 16)))

// ---------------------------------------------------------------------------
// Conversion: z -> bf16; W1[g,d,h] -> W1t[g,h,d] bf16; Wc[d,g] -> Wct[g,d]
// ---------------------------------------------------------------------------
__global__ __launch_bounds__(256) void k_convert(
    const float* __restrict__ z, const float* __restrict__ W1,
    const float* __restrict__ Wc, unsigned short* __restrict__ zb,
    unsigned short* __restrict__ w1t, unsigned short* __restrict__ wct) {
  int bid = blockIdx.x;
  int tid = threadIdx.x;
  if (bid < 16384) {
    size_t i = ((size_t)bid * 256 + tid) * 8;
    const float4* p = (const float4*)(z + i);
    float4 a = p[0], b = p[1];
    ushortx8 r;
    r[0] = f2bf(a.x); r[1] = f2bf(a.y); r[2] = f2bf(a.z); r[3] = f2bf(a.w);
    r[4] = f2bf(b.x); r[5] = f2bf(b.y); r[6] = f2bf(b.z); r[7] = f2bf(b.w);
    *(ushortx8*)(zb + i) = r;
  } else if (bid < 16384 + 1024) {
    // W1 transpose via 32x32 LDS tile, both sides coalesced
    __shared__ float tile[32][33];
    int b = bid - 16384;
    int gg = b >> 6;
    int t = b & 63;
    int d0 = (t >> 2) * 32;
    int h0 = (t & 3) * 32;
    int tx = tid & 31, ty = tid >> 5;
#pragma unroll
    for (int r = 0; r < 4; ++r) {
      int d = d0 + r * 8 + ty;
      tile[r * 8 + ty][tx] = W1[(gg << 16) + d * 128 + h0 + tx];
    }
    __syncthreads();
#pragma unroll
    for (int r = 0; r < 4; ++r) {
      int h = h0 + r * 8 + ty;
      w1t[(gg << 16) + h * 512 + d0 + tx] = f2bf(tile[tx][r * 8 + ty]);
    }
  } else {
#pragma unroll
    for (int j = 0; j < 32; ++j) {
      int i = j * 256 + tid;
      wct[(i & 15) * 512 + (i >> 4)] = f2bf(Wc[i]);
    }
  }
}

// ---------------------------------------------------------------------------
// Logits: logits = z @ Wc + bc, softmax. 512 blocks x 128 rows.
// ---------------------------------------------------------------------------
__global__ __launch_bounds__(256) void k_logits(
    const unsigned short* __restrict__ zb,
    const unsigned short* __restrict__ wct, const float* __restrict__ bc,
    float* __restrict__ out) {
  __shared__ alignas(16) char lds[16384];
  const int tid = threadIdx.x;
  const int wq = tid >> 6;
  const int ln = tid & 63;
  const int l15 = ln & 15;
  const int l4 = ln >> 4;
  const int c8s = (((tid & 7) ^ ((tid >> 3) & 7))) * 8;
  const int mbase = blockIdx.x * 128;
  const unsigned short* ag = zb + (size_t)(mbase + (tid >> 3)) * 512 + c8s;
  const unsigned short* wb = wct + l15 * 512 + l4 * 8;
  f32x4 acc2[2] = {};
  for (int kt = 0; kt < 8; ++kt) {
    const int ko = kt * 64;
#pragma unroll
    for (int it = 0; it < 4; ++it)
      GLOAD16(ag + it * 32 * 512 + ko, lds + it * 4096 + tid * 16);
    bf16x8 bfr0 = *(const bf16x8*)(wb + ko);
    bf16x8 bfr1 = *(const bf16x8*)(wb + ko + 32);
    __syncthreads();
#pragma unroll
    for (int rt = 0; rt < 2; ++rt) {
      bf16x8 a0 = SWZ_FRAG(lds, wq * 32 + rt * 16 + l15, l4);
      acc2[rt] =
          __builtin_amdgcn_mfma_f32_16x16x32_bf16(a0, bfr0, acc2[rt], 0, 0, 0);
      bf16x8 a1 = SWZ_FRAG(lds, wq * 32 + rt * 16 + l15, 4 + l4);
      acc2[rt] =
          __builtin_amdgcn_mfma_f32_16x16x32_bf16(a1, bfr1, acc2[rt], 0, 0, 0);
    }
    __syncthreads();
  }
  float bcv = bc[l15];
#pragma unroll
  for (int rt = 0; rt < 2; ++rt) {
#pragma unroll
    for (int i = 0; i < 4; ++i) {
      int row = wq * 32 + rt * 16 + l4 * 4 + i;
      float lg = acc2[rt][i] + bcv;
      float mx = lg;
#pragma unroll
      for (int off = 1; off < 16; off <<= 1)
        mx = fmaxf(mx, __shfl_xor(mx, off, 16));
      float ex = __expf(lg - mx);
      float sm = ex;
#pragma unroll
      for (int off = 1; off < 16; off <<= 1)
        sm += __shfl_xor(sm, off, 16);
      size_t ro = (size_t)(mbase + row) * 16 + l15;
      out[ro] = lg;
      out[1048576 + ro] = ex / sm;
    }
  }
}

// ---------------------------------------------------------------------------
// Expert kernel: 512 threads (8 waves). Block = 128 rows x 256 cols
// (expert pair p -> experts 2p, 2p+1). Wave (wr = wv&1, wc = wv>>2? no:
// wc = wv>>1) covers rows [wr*64,+64) x cols [wc*64,+64). m-major grid:
// 8 sibling blocks share the z-tile via L2; w1t (2MB) is L2-resident.
// A (16KB) + B (32KB) staged per kt via global_load_lds, XOR-swizzled;
// 48KB LDS -> 3 blocks/CU = 24 waves/CU.
// ---------------------------------------------------------------------------
__global__ __launch_bounds__(512, 6) void k_expert(
    const unsigned short* __restrict__ zb,   // [65536][512] bf16
    const unsigned short* __restrict__ w1t,  // [16][128][512] bf16
    const float* __restrict__ b1, const float* __restrict__ w2,
    const float* __restrict__ b2, float* __restrict__ out) {
  __shared__ alignas(16) char lds[16384 + 32768];  // A | B ; ylds overlays A
  const int tid = threadIdx.x;
  const int p = blockIdx.x & 7;
  const int mbase = (blockIdx.x >> 3) * 128;
  const int wv = tid >> 6;
  const int ln = tid & 63;
  const int l15 = ln & 15;
  const int l4 = ln >> 4;
  const int wr = wv & 1;   // row half
  const int wc = wv >> 1;  // col quarter (0..3); expert = p*2 + (wc>>1)
  const int e = p * 2 + (wc >> 1);
  char* ldsB = lds + 16384;

  // staging: thread t covers row (a*64 + t>>3), slot t&7, src col8 swizzled
  const int c8s = (((tid & 7) ^ ((tid >> 3) & 7))) * 8;
  const unsigned short* ag = zb + (size_t)(mbase + (tid >> 3)) * 512 + c8s;
  const unsigned short* bg = w1t + p * 131072 + (tid >> 3) * 512 + c8s;

  f32x4 acc[4][4] = {};
  for (int kt = 0; kt < 8; ++kt) {
    const int ko = kt * 64;
#pragma unroll
    for (int it = 0; it < 2; ++it)
      GLOAD16(ag + it * 64 * 512 + ko, lds + it * 8192 + tid * 16);
#pragma unroll
    for (int it = 0; it < 4; ++it)
      GLOAD16(bg + it * 64 * 512 + ko, ldsB + it * 8192 + tid * 16);
    __syncthreads();
#pragma unroll
    for (int ks = 0; ks < 2; ++ks) {
      bf16x8 af[4];
#pragma unroll
      for (int rt = 0; rt < 4; ++rt)
        af[rt] = SWZ_FRAG(lds, wr * 64 + rt * 16 + l15, ks * 4 + l4);
#pragma unroll
      for (int ct = 0; ct < 4; ++ct) {
        bf16x8 bf = SWZ_FRAG(ldsB, wc * 64 + ct * 16 + l15, ks * 4 + l4);
#pragma unroll
        for (int rt = 0; rt < 4; ++rt)
          acc[rt][ct] = __builtin_amdgcn_mfma_f32_16x16x32_bf16(
              af[rt], bf, acc[rt][ct], 0, 0, 0);
      }
    }
    __syncthreads();
  }
  // epilogue: partial y over this wave's 64 cols -> ylds, then combine the
  // two col-quarters of each expert.
  float b1v[4], w2v[4];
#pragma unroll
  for (int ct = 0; ct < 4; ++ct) {
    int n = (wc & 1) * 64 + ct * 16 + l15;  // col within expert e
    b1v[ct] = b1[e * 128 + n];
    w2v[ct] = w2[e * 128 + n];
  }
  float* ylds = (float*)lds;  // [4 col-quarters][128 rows], overlays A buf
#pragma unroll
  for (int rt = 0; rt < 4; ++rt) {
#pragma unroll
    for (int i = 0; i < 4; ++i) {
      float s = 0.0f;
#pragma unroll
      for (int ct = 0; ct < 4; ++ct)
        s += gelu_s(acc[rt][ct][i] + b1v[ct]) * w2v[ct];
#pragma unroll
      for (int off = 1; off < 16; off <<= 1)
        s += __shfl_xor(s, off, 16);
      if (l15 == 0) ylds[wc * 128 + wr * 64 + rt * 16 + l4 * 4 + i] = s;
    }
  }
  __syncthreads();
  if (tid < 256) {
    int row = tid & 127, ei = tid >> 7;
    float y = ylds[ei * 256 + row] + ylds[ei * 256 + 128 + row] +
              b2[p * 2 + ei];
    out[(size_t)2097152 + (size_t)(mbase + row) * 16 + p * 2 + ei] = y;
  }
}

// ---------------------------------------------------------------------------
extern "C" void kernel_launch(void* const* d_in, const int* in_sizes, int n_in,
                              void* d_out, int out_size, void* d_ws,
                              size_t ws_size, hipStream_t stream) {
  const float* z = (const float*)d_in[0];
  const float* Wc = (const float*)d_in[1];
  const float* bc = (const float*)d_in[2];
  const float* W1 = (const float*)d_in[3];
  const float* b1 = (const float*)d_in[4];
  const float* W2 = (const float*)d_in[5];
  const float* b2 = (const float*)d_in[6];
  float* out = (float*)d_out;

  unsigned short* zb = (unsigned short*)d_ws;            // 64 MB
  unsigned short* w1t = zb + (size_t)65536 * 512;        // 2 MB
  unsigned short* wct = w1t + (size_t)16 * 128 * 512;    // 16 KB

  k_convert<<<16384 + 1024 + 1, 256, 0, stream>>>(z, W1, Wc, zb, w1t, wct);
  k_logits<<<512, 256, 0, stream>>>(zb, wct, bc, out);
  k_expert<<<512 * 8, 512, 0, stream>>>(zb, w1t, b1, W2, b2, out);
}